// Round 1
// baseline (352.247 us; speedup 1.0000x reference)
//
#include <hip/hip_runtime.h>
#include <math.h>

typedef unsigned short u16;
typedef unsigned int u32;

#define N_ROWS 8192
#define DDIM 512
#define HDIM 1024
#define ODIM 512
#define NEXP 8
#define MAXPAIRS (N_ROWS * 2)          // 16384
#define MAXPOS (MAXPAIRS + NEXP * 128) // 17408 (per-expert segments 128-aligned)
#define MAXTILES (MAXPOS / 128)        // 136

// small-region word indices (in d_ws)
#define SM_CNT 0   // 8 ints: expert lengths
#define SM_CUR 8   // 8 ints: scatter cursors
#define SM_AOFF 16 // 9 ints: aligned bucket offsets
#define SM_GSUM 32 // 8 floats: sum of gates per expert
#define SM_LSUM 40 // 8 floats: sum of load_probs per expert
#define SM_WORDS 64

using short8 = __attribute__((ext_vector_type(8))) short;
using float4v = __attribute__((ext_vector_type(4))) float;

__device__ __forceinline__ u16 f2bf(float f) {
    union { float f; u32 u; } v; v.f = f;
    u32 u = v.u;
    return (u16)((u + 0x7fffu + ((u >> 16) & 1u)) >> 16);
}

// ---------------- init ----------------
__global__ __launch_bounds__(256) void init_kernel(int* small, int* bucket_rows, float* zeropage) {
    int i = blockIdx.x * 256 + threadIdx.x;
    if (i < SM_WORDS) small[i] = 0;
    if (i < 512) zeropage[i] = 0.f; // 2 KB of zeros (gather target for padded rows)
    if (i < MAXPOS) bucket_rows[i] = -1;
}

// ---------------- weight conversion ----------------
__global__ __launch_bounds__(256) void convert_w_kernel(const float* __restrict__ W1, const float* __restrict__ W2,
                                                        u16* __restrict__ W1b, u16* __restrict__ W2b) {
    const size_t n4 = (size_t)NEXP * HDIM * DDIM / 4; // 1048576 float4s per matrix
    size_t i = (size_t)blockIdx.x * 256 + threadIdx.x;
    const float* src; u16* dst;
    if (i < n4) { src = W1; dst = W1b; } else { src = W2; dst = W2b; i -= n4; }
    float4 v = ((const float4*)src)[i];
    ushort4 o;
    o.x = f2bf(v.x); o.y = f2bf(v.y); o.z = f2bf(v.z); o.w = f2bf(v.w);
    ((ushort4*)dst)[i] = o;
}

__global__ __launch_bounds__(256) void transpose_ow_kernel(const float* __restrict__ ow, u16* __restrict__ owT) {
    // ow[d][o] (512x512) -> owT[o][d] bf16
    __shared__ float tile[32][33];
    int bx = blockIdx.x * 32, by = blockIdx.y * 32;
    int tx = threadIdx.x & 31, ty = threadIdx.x >> 5; // 32 x 8
    for (int r = ty; r < 32; r += 8) tile[r][tx] = ow[(size_t)(by + r) * ODIM + bx + tx];
    __syncthreads();
    for (int r = ty; r < 32; r += 8) owT[(size_t)(bx + r) * DDIM + by + tx] = f2bf(tile[tx][r]);
}

// ---------------- layernorm + gating ----------------
__global__ __launch_bounds__(256) void gating_kernel(
    const float* __restrict__ x, const float* __restrict__ noise,
    const float* __restrict__ norm_w, const float* __restrict__ norm_b,
    const float* __restrict__ w_gate, const float* __restrict__ w_noise,
    u16* __restrict__ xnorm_bf, u16* __restrict__ x_bf,
    int* __restrict__ pair_expert, float* __restrict__ pair_gate,
    int* __restrict__ small)
{
    __shared__ float wgT[NEXP * DDIM]; // [e][d] transposed -> conflict-free lane-stride-1 reads
    __shared__ float wnT[NEXP * DDIM];
    __shared__ float blk_g[NEXP];
    __shared__ float blk_l[NEXP];
    __shared__ int blk_c[NEXP];
    float* smf = (float*)small;

    int tid = threadIdx.x;
    for (int i = tid; i < NEXP * DDIM; i += 256) {
        int d = i >> 3, e = i & 7;
        wgT[e * DDIM + d] = w_gate[i];
        wnT[e * DDIM + d] = w_noise[i];
    }
    if (tid < NEXP) { blk_g[tid] = 0.f; blk_l[tid] = 0.f; blk_c[tid] = 0; }
    __syncthreads();

    int wave = tid >> 6, lane = tid & 63;
    float nw[8], nb[8];
#pragma unroll
    for (int j = 0; j < 8; j++) { nw[j] = norm_w[j * 64 + lane]; nb[j] = norm_b[j * 64 + lane]; }

    for (int r = 0; r < 4; ++r) {
        int row = blockIdx.x * 16 + wave * 4 + r;
        const float* xr = x + (size_t)row * DDIM;
        float xv[8], s = 0.f, s2 = 0.f;
#pragma unroll
        for (int j = 0; j < 8; j++) { float v = xr[j * 64 + lane]; xv[j] = v; s += v; s2 += v * v; }
#pragma unroll
        for (int o = 32; o; o >>= 1) { s += __shfl_xor(s, o, 64); s2 += __shfl_xor(s2, o, 64); }
        float mu = s * (1.f / DDIM);
        float var = s2 * (1.f / DDIM) - mu * mu;
        float rstd = rsqrtf(var + 1e-6f);

        float acc[16];
#pragma unroll
        for (int e = 0; e < 16; e++) acc[e] = 0.f;
#pragma unroll
        for (int j = 0; j < 8; j++) {
            float v = (xv[j] - mu) * rstd * nw[j] + nb[j];
            int d = j * 64 + lane;
            xnorm_bf[(size_t)row * DDIM + d] = f2bf(v);
            x_bf[(size_t)row * DDIM + d] = f2bf(xv[j]);
#pragma unroll
            for (int e = 0; e < 8; e++) {
                acc[e] += v * wgT[e * DDIM + d];
                acc[8 + e] += v * wnT[e * DDIM + d];
            }
        }
#pragma unroll
        for (int e = 0; e < 16; e++)
#pragma unroll
            for (int o = 32; o; o >>= 1) acc[e] += __shfl_xor(acc[e], o, 64);

        // all lanes now hold the full 16 logits; finish scalar gating math
        float cl[8], sd[8], nz[8];
#pragma unroll
        for (int e = 0; e < 8; e++) {
            cl[e] = acc[e];
            float t = acc[8 + e];
            float sp = fmaxf(t, 0.f) + log1pf(expf(-fabsf(t))); // stable softplus
            sd[e] = sp + 0.01f;
            nz[e] = cl[e] + noise[(size_t)row * NEXP + e] * sd[e];
        }
        // top-3 (strict > gives lowest-index tie-break, matching lax.top_k)
        int idx[3]; float val[3]; u32 msk = 0;
#pragma unroll
        for (int t = 0; t < 3; t++) {
            float best = -INFINITY; int bi = 0;
#pragma unroll
            for (int e = 0; e < 8; e++)
                if (!((msk >> e) & 1) && nz[e] > best) { best = nz[e]; bi = e; }
            idx[t] = bi; val[t] = best; msk |= 1u << bi;
        }
        float e1 = expf(val[1] - val[0]);
        float g0 = 1.f / (1.f + e1), g1 = e1 / (1.f + e1);
        float thr_in = val[2], thr_out = val[1];

        if (lane == 0) {
            pair_expert[row * 2] = idx[0]; pair_gate[row * 2] = g0;
            pair_expert[row * 2 + 1] = idx[1]; pair_gate[row * 2 + 1] = g1;
            atomicAdd(&blk_g[idx[0]], g0); atomicAdd(&blk_g[idx[1]], g1);
            atomicAdd(&blk_c[idx[0]], 1); atomicAdd(&blk_c[idx[1]], 1);
#pragma unroll
            for (int e = 0; e < 8; e++) {
                float thr = (nz[e] > thr_in) ? thr_in : thr_out;
                float z = (cl[e] - thr) / sd[e];
                float p = 0.5f * (1.f + erff(z * 0.70710678118654752f));
                atomicAdd(&blk_l[e], p);
            }
        }
    }
    __syncthreads();
    if (tid < NEXP) {
        atomicAdd(smf + SM_GSUM + tid, blk_g[tid]);
        atomicAdd(smf + SM_LSUM + tid, blk_l[tid]);
        atomicAdd(&small[SM_CNT + tid], blk_c[tid]);
    }
}

// ---------------- bucket prefix + scatter ----------------
__global__ void prefix_kernel(int* small) {
    if (threadIdx.x == 0 && blockIdx.x == 0) {
        int acc = 0;
        small[SM_AOFF] = 0;
        for (int e = 0; e < NEXP; e++) {
            acc += (small[SM_CNT + e] + 127) & ~127;
            small[SM_AOFF + e + 1] = acc;
        }
    }
}

__global__ __launch_bounds__(256) void scatter_kernel(const int* __restrict__ pair_expert, int* small,
                                                      int* __restrict__ bucket_rows, int* __restrict__ pair_pos) {
    int p = blockIdx.x * 256 + threadIdx.x;
    if (p >= MAXPAIRS) return;
    int e = pair_expert[p];
    int pos = small[SM_AOFF + e] + atomicAdd(&small[SM_CUR + e], 1);
    bucket_rows[pos] = p >> 1;
    pair_pos[p] = pos;
}

// ---------------- MFMA GEMM (A . B^T), 128x128 tile, BK=32 ----------------
// MODE 0: gathered x_norm @ W1[e]^T, +b1, SiLU, bf16 store to a_buf   (K=512,  N=1024)
// MODE 1: a_buf @ W2[e]^T, fp32 store to ypair                        (K=1024, N=512)
// MODE 2: x_bf @ owT^T, fp32 store to y                               (K=512,  N=512)
template <int MODE>
__global__ __launch_bounds__(256) void gemm_kernel(
    const u16* __restrict__ A, const u16* __restrict__ Bw,
    const int* __restrict__ bucket_rows, const int* __restrict__ small,
    const float* __restrict__ bias, const u16* __restrict__ zeropage,
    u16* __restrict__ out_bf, float* __restrict__ out_f)
{
    constexpr int KD = (MODE == 1) ? 1024 : 512;
    constexpr int ND = (MODE == 0) ? 1024 : 512;
    constexpr int SA = 40; // padded LDS row stride in shorts (80B: 16B-aligned, breaks pow2 banks)
    __shared__ __align__(16) u16 As[128 * SA];
    __shared__ __align__(16) u16 Bs[128 * SA];

    int tid = threadIdx.x;
    int e = 0;
    int base = blockIdx.x * 128;
    if constexpr (MODE == 0 || MODE == 1) {
        if (base >= small[SM_AOFF + 8]) return;
        while (e < 7 && base >= small[SM_AOFF + e + 1]) ++e;
    }

    const int srow = tid >> 2;       // 0..63
    const int scol = (tid & 3) * 8;  // 0,8,16,24 (x8 bf16 = 16B)
    const u16 *ap0, *ap1;
    if constexpr (MODE == 0) {
        int r0 = bucket_rows[base + srow];
        int r1 = bucket_rows[base + srow + 64];
        ap0 = (r0 < 0) ? zeropage : A + (size_t)r0 * KD;
        ap1 = (r1 < 0) ? zeropage : A + (size_t)r1 * KD;
    } else {
        ap0 = A + (size_t)(base + srow) * KD;
        ap1 = A + (size_t)(base + srow + 64) * KD;
    }
    const u16* Bsel = Bw + ((MODE == 2) ? 0 : (size_t)e * ND * KD);
    int bn = blockIdx.y * 128;
    const u16* bp0 = Bsel + (size_t)(bn + srow) * KD + scol;
    const u16* bp1 = Bsel + (size_t)(bn + srow + 64) * KD + scol;
    ap0 += scol; ap1 += scol;

    int wave = tid >> 6, lane = tid & 63;
    int wm = (wave & 1) * 64, wn = (wave >> 1) * 64;
    int fr = lane & 15, kg = (lane >> 4) * 8;

    float4v acc[4][4];
#pragma unroll
    for (int i = 0; i < 4; i++)
#pragma unroll
        for (int j = 0; j < 4; j++) acc[i][j] = (float4v){0.f, 0.f, 0.f, 0.f};

    for (int k0 = 0; k0 < KD; k0 += 32) {
        uint4 a0 = *(const uint4*)(ap0 + k0);
        uint4 a1 = *(const uint4*)(ap1 + k0);
        uint4 b0 = *(const uint4*)(bp0 + k0);
        uint4 b1 = *(const uint4*)(bp1 + k0);
        __syncthreads();
        *(uint4*)&As[srow * SA + scol] = a0;
        *(uint4*)&As[(srow + 64) * SA + scol] = a1;
        *(uint4*)&Bs[srow * SA + scol] = b0;
        *(uint4*)&Bs[(srow + 64) * SA + scol] = b1;
        __syncthreads();
        short8 af[4], bf[4];
#pragma unroll
        for (int mt = 0; mt < 4; mt++) af[mt] = *(const short8*)&As[(wm + mt * 16 + fr) * SA + kg];
#pragma unroll
        for (int nt = 0; nt < 4; nt++) bf[nt] = *(const short8*)&Bs[(wn + nt * 16 + fr) * SA + kg];
#pragma unroll
        for (int mt = 0; mt < 4; mt++)
#pragma unroll
            for (int nt = 0; nt < 4; nt++)
                acc[mt][nt] = __builtin_amdgcn_mfma_f32_16x16x32_bf16(af[mt], bf[nt], acc[mt][nt], 0, 0, 0);
    }

    // epilogue: C/D layout col=lane&15, row=(lane>>4)*4+reg (m89-verified)
    int rbase = (lane >> 4) * 4, c16 = lane & 15;
#pragma unroll
    for (int nt = 0; nt < 4; nt++) {
        int gn = bn + wn + nt * 16 + c16;
        float bv = 0.f;
        if constexpr (MODE == 0) bv = bias[e * ND + gn];
#pragma unroll
        for (int mt = 0; mt < 4; mt++) {
            int gm = base + wm + mt * 16 + rbase;
#pragma unroll
            for (int r = 0; r < 4; r++) {
                float v = acc[mt][nt][r];
                if constexpr (MODE == 0) {
                    float h = v + bv;
                    float a = h / (1.f + expf(-h)); // SiLU
                    out_bf[(size_t)(gm + r) * ND + gn] = f2bf(a);
                } else {
                    out_f[(size_t)(gm + r) * ND + gn] = v;
                }
            }
        }
    }
}

// ---------------- combine: y += sum_k gate_k * (ypair_k + b2[e_k]) ----------------
__global__ __launch_bounds__(128) void combine_kernel(
    float* __restrict__ y, const float* __restrict__ ypair,
    const int* __restrict__ pair_expert, const float* __restrict__ pair_gate,
    const int* __restrict__ pair_pos, const float* __restrict__ b2)
{
    int row = blockIdx.x;
    int e0 = pair_expert[row * 2], e1 = pair_expert[row * 2 + 1];
    float g0 = pair_gate[row * 2], g1 = pair_gate[row * 2 + 1];
    int p0 = pair_pos[row * 2], p1 = pair_pos[row * 2 + 1];
    int i = threadIdx.x; // 128 threads x float4 = 512 cols
    const float4* a0 = (const float4*)(ypair + (size_t)p0 * ODIM);
    const float4* a1 = (const float4*)(ypair + (size_t)p1 * ODIM);
    const float4* c0 = (const float4*)(b2 + (size_t)e0 * ODIM);
    const float4* c1 = (const float4*)(b2 + (size_t)e1 * ODIM);
    float4* yr = (float4*)(y + (size_t)row * ODIM);
    float4 v = yr[i], u0 = a0[i], u1 = a1[i], w0 = c0[i], w1 = c1[i];
    v.x += g0 * (u0.x + w0.x) + g1 * (u1.x + w1.x);
    v.y += g0 * (u0.y + w0.y) + g1 * (u1.y + w1.y);
    v.z += g0 * (u0.z + w0.z) + g1 * (u1.z + w1.z);
    v.w += g0 * (u0.w + w0.w) + g1 * (u1.w + w1.w);
    yr[i] = v;
}

// ---------------- loss + load ----------------
__global__ void loss_kernel(const int* __restrict__ small, float* __restrict__ out_loss, float* __restrict__ out_load) {
    if (threadIdx.x == 0 && blockIdx.x == 0) {
        const float* gs = (const float*)small + SM_GSUM;
        const float* ls = (const float*)small + SM_LSUM;
        float cv[2];
        for (int t = 0; t < 2; t++) {
            const float* v = t ? ls : gs;
            float m = 0.f;
            for (int e = 0; e < NEXP; e++) m += v[e];
            m *= (1.f / NEXP);
            float var = 0.f;
            for (int e = 0; e < NEXP; e++) { float d = v[e] - m; var += d * d; }
            var *= (1.f / NEXP);
            cv[t] = var / (m * m + 1e-10f);
        }
        out_loss[0] = 0.01f * (cv[0] + cv[1]);
        int tot = 0;
        for (int e = 0; e < NEXP; e++) tot += small[SM_CNT + e];
        float inv = 1.f / (float)tot;
        for (int e = 0; e < NEXP; e++) out_load[e] = (float)small[SM_CNT + e] * inv;
    }
}

extern "C" void kernel_launch(void* const* d_in, const int* in_sizes, int n_in,
                              void* d_out, int out_size, void* d_ws, size_t ws_size,
                              hipStream_t stream)
{
    (void)in_sizes; (void)n_in; (void)out_size; (void)ws_size;
    const float* x = (const float*)d_in[0];
    // d_in[1] x_offsets, d_in[2] max_seq_len: unused by the reference math
    const float* noise = (const float*)d_in[3];
    const float* norm_w = (const float*)d_in[4];
    const float* norm_b = (const float*)d_in[5];
    const float* w_gate = (const float*)d_in[6];
    const float* w_noise = (const float*)d_in[7];
    const float* W1 = (const float*)d_in[8];
    const float* b1 = (const float*)d_in[9];
    const float* W2 = (const float*)d_in[10];
    const float* b2 = (const float*)d_in[11];
    const float* ow = (const float*)d_in[12];

    float* y = (float*)d_out;
    float* out_loss = y + (size_t)N_ROWS * ODIM;
    float* out_load = out_loss + 1;

    char* ws = (char*)d_ws;
    size_t off = 0;
    auto alloc = [&](size_t b) { size_t p = off; off = (off + b + 255) & ~(size_t)255; return p; };
    u16* xnorm_bf = (u16*)(ws + alloc((size_t)N_ROWS * DDIM * 2));
    u16* x_bf     = (u16*)(ws + alloc((size_t)N_ROWS * DDIM * 2));
    u16* W1b      = (u16*)(ws + alloc((size_t)NEXP * HDIM * DDIM * 2));
    u16* W2b      = (u16*)(ws + alloc((size_t)NEXP * ODIM * HDIM * 2));
    u16* owT      = (u16*)(ws + alloc((size_t)DDIM * ODIM * 2));
    u16* a_buf    = (u16*)(ws + alloc((size_t)MAXPOS * HDIM * 2));
    float* ypair  = (float*)(ws + alloc((size_t)MAXPOS * ODIM * 4));
    int* pair_expert = (int*)(ws + alloc((size_t)MAXPAIRS * 4));
    float* pair_gate = (float*)(ws + alloc((size_t)MAXPAIRS * 4));
    int* pair_pos    = (int*)(ws + alloc((size_t)MAXPAIRS * 4));
    int* bucket_rows = (int*)(ws + alloc((size_t)MAXPOS * 4));
    int* small       = (int*)(ws + alloc(SM_WORDS * 4));
    float* zeropage  = (float*)(ws + alloc(2048));

    init_kernel<<<MAXPOS / 256, 256, 0, stream>>>(small, bucket_rows, zeropage);
    convert_w_kernel<<<8192, 256, 0, stream>>>(W1, W2, W1b, W2b);
    transpose_ow_kernel<<<dim3(16, 16), 256, 0, stream>>>(ow, owT);
    gating_kernel<<<N_ROWS / 16, 256, 0, stream>>>(x, noise, norm_w, norm_b, w_gate, w_noise,
                                                   xnorm_bf, x_bf, pair_expert, pair_gate, small);
    prefix_kernel<<<1, 1, 0, stream>>>(small);
    scatter_kernel<<<MAXPAIRS / 256, 256, 0, stream>>>(pair_expert, small, bucket_rows, pair_pos);
    gemm_kernel<0><<<dim3(MAXTILES, HDIM / 128), 256, 0, stream>>>(xnorm_bf, W1b, bucket_rows, small,
                                                                   b1, (const u16*)zeropage, a_buf, nullptr);
    gemm_kernel<1><<<dim3(MAXTILES, ODIM / 128), 256, 0, stream>>>(a_buf, W2b, bucket_rows, small,
                                                                   nullptr, (const u16*)zeropage, nullptr, ypair);
    gemm_kernel<2><<<dim3(N_ROWS / 128, ODIM / 128), 256, 0, stream>>>(x_bf, owT, bucket_rows, small,
                                                                       nullptr, (const u16*)zeropage, nullptr, y);
    combine_kernel<<<N_ROWS, 128, 0, stream>>>(y, ypair, pair_expert, pair_gate, pair_pos, b2);
    loss_kernel<<<1, 64, 0, stream>>>(small, out_loss, out_load);
}

// Round 2
// 279.770 us; speedup vs baseline: 1.2591x; 1.2591x over previous
//
#include <hip/hip_runtime.h>
#include <math.h>

typedef unsigned short u16;
typedef unsigned int u32;

#define N_ROWS 8192
#define DDIM 512
#define HDIM 1024
#define ODIM 512
#define NEXP 8
#define MAXPAIRS (N_ROWS * 2)          // 16384
#define MAXPOS (MAXPAIRS + NEXP * 128) // 17408 (per-expert segments 128-aligned)
#define MAXTILES (MAXPOS / 128)        // 136

// small-region word indices (in d_ws)
#define SM_CNT 0   // 8 ints: expert lengths
#define SM_CUR 8   // 8 ints: scatter cursors
#define SM_AOFF 16 // 9 ints: aligned bucket offsets
#define SM_GSUM 32 // 8 floats: sum of gates per expert
#define SM_LSUM 40 // 8 floats: sum of load_probs per expert
#define SM_WORDS 64

using short8 = __attribute__((ext_vector_type(8))) short;
using float4v = __attribute__((ext_vector_type(4))) float;

__device__ __forceinline__ u16 f2bf(float f) {
    union { float f; u32 u; } v; v.f = f;
    u32 u = v.u;
    return (u16)((u + 0x7fffu + ((u >> 16) & 1u)) >> 16);
}

// ---------------- init ----------------
__global__ __launch_bounds__(256) void init_kernel(int* small, int* bucket_rows, float* zeropage) {
    int i = blockIdx.x * 256 + threadIdx.x;
    if (i < SM_WORDS) small[i] = 0;
    if (i < 512) zeropage[i] = 0.f; // 2 KB of zeros (gather target for padded rows)
    if (i < MAXPOS) bucket_rows[i] = -1;
}

// ---------------- weight conversion ----------------
__global__ __launch_bounds__(256) void convert_w_kernel(const float* __restrict__ W1, const float* __restrict__ W2,
                                                        u16* __restrict__ W1b, u16* __restrict__ W2b) {
    const size_t n4 = (size_t)NEXP * HDIM * DDIM / 4; // 1048576 float4s per matrix
    size_t i = (size_t)blockIdx.x * 256 + threadIdx.x;
    const float* src; u16* dst;
    if (i < n4) { src = W1; dst = W1b; } else { src = W2; dst = W2b; i -= n4; }
    float4 v = ((const float4*)src)[i];
    ushort4 o;
    o.x = f2bf(v.x); o.y = f2bf(v.y); o.z = f2bf(v.z); o.w = f2bf(v.w);
    ((ushort4*)dst)[i] = o;
}

__global__ __launch_bounds__(256) void transpose_ow_kernel(const float* __restrict__ ow, u16* __restrict__ owT) {
    // ow[d][o] (512x512) -> owT[o][d] bf16
    __shared__ float tile[32][33];
    int bx = blockIdx.x * 32, by = blockIdx.y * 32;
    int tx = threadIdx.x & 31, ty = threadIdx.x >> 5; // 32 x 8
    for (int r = ty; r < 32; r += 8) tile[r][tx] = ow[(size_t)(by + r) * ODIM + bx + tx];
    __syncthreads();
    for (int r = ty; r < 32; r += 8) owT[(size_t)(bx + r) * DDIM + by + tx] = f2bf(tile[tx][r]);
}

// ---------------- layernorm + gating ----------------
__global__ __launch_bounds__(256) void gating_kernel(
    const float* __restrict__ x, const float* __restrict__ noise,
    const float* __restrict__ norm_w, const float* __restrict__ norm_b,
    const float* __restrict__ w_gate, const float* __restrict__ w_noise,
    u16* __restrict__ xnorm_bf, u16* __restrict__ x_bf,
    int* __restrict__ pair_expert, float* __restrict__ pair_gate,
    int* __restrict__ small)
{
    __shared__ float wgT[NEXP * DDIM]; // [e][d] transposed -> conflict-free lane-stride-1 reads
    __shared__ float wnT[NEXP * DDIM];
    __shared__ float blk_g[NEXP];
    __shared__ float blk_l[NEXP];
    __shared__ int blk_c[NEXP];
    float* smf = (float*)small;

    int tid = threadIdx.x;
    for (int i = tid; i < NEXP * DDIM; i += 256) {
        int d = i >> 3, e = i & 7;
        wgT[e * DDIM + d] = w_gate[i];
        wnT[e * DDIM + d] = w_noise[i];
    }
    if (tid < NEXP) { blk_g[tid] = 0.f; blk_l[tid] = 0.f; blk_c[tid] = 0; }
    __syncthreads();

    int wave = tid >> 6, lane = tid & 63;
    float nw[8], nb[8];
#pragma unroll
    for (int j = 0; j < 8; j++) { nw[j] = norm_w[j * 64 + lane]; nb[j] = norm_b[j * 64 + lane]; }

    for (int r = 0; r < 4; ++r) {
        int row = blockIdx.x * 16 + wave * 4 + r;
        const float* xr = x + (size_t)row * DDIM;
        float xv[8], s = 0.f, s2 = 0.f;
#pragma unroll
        for (int j = 0; j < 8; j++) { float v = xr[j * 64 + lane]; xv[j] = v; s += v; s2 += v * v; }
#pragma unroll
        for (int o = 32; o; o >>= 1) { s += __shfl_xor(s, o, 64); s2 += __shfl_xor(s2, o, 64); }
        float mu = s * (1.f / DDIM);
        float var = s2 * (1.f / DDIM) - mu * mu;
        float rstd = rsqrtf(var + 1e-6f);

        float acc[16];
#pragma unroll
        for (int e = 0; e < 16; e++) acc[e] = 0.f;
#pragma unroll
        for (int j = 0; j < 8; j++) {
            float v = (xv[j] - mu) * rstd * nw[j] + nb[j];
            int d = j * 64 + lane;
            xnorm_bf[(size_t)row * DDIM + d] = f2bf(v);
            x_bf[(size_t)row * DDIM + d] = f2bf(xv[j]);
#pragma unroll
            for (int e = 0; e < 8; e++) {
                acc[e] += v * wgT[e * DDIM + d];
                acc[8 + e] += v * wnT[e * DDIM + d];
            }
        }
#pragma unroll
        for (int e = 0; e < 16; e++)
#pragma unroll
            for (int o = 32; o; o >>= 1) acc[e] += __shfl_xor(acc[e], o, 64);

        // all lanes now hold the full 16 logits; finish scalar gating math
        float cl[8], sd[8], nz[8];
#pragma unroll
        for (int e = 0; e < 8; e++) {
            cl[e] = acc[e];
            float t = acc[8 + e];
            float sp = fmaxf(t, 0.f) + log1pf(expf(-fabsf(t))); // stable softplus
            sd[e] = sp + 0.01f;
            nz[e] = cl[e] + noise[(size_t)row * NEXP + e] * sd[e];
        }
        // top-3 (strict > gives lowest-index tie-break, matching lax.top_k)
        int idx[3]; float val[3]; u32 msk = 0;
#pragma unroll
        for (int t = 0; t < 3; t++) {
            float best = -INFINITY; int bi = 0;
#pragma unroll
            for (int e = 0; e < 8; e++)
                if (!((msk >> e) & 1) && nz[e] > best) { best = nz[e]; bi = e; }
            idx[t] = bi; val[t] = best; msk |= 1u << bi;
        }
        float e1 = expf(val[1] - val[0]);
        float g0 = 1.f / (1.f + e1), g1 = e1 / (1.f + e1);
        float thr_in = val[2], thr_out = val[1];

        if (lane == 0) {
            pair_expert[row * 2] = idx[0]; pair_gate[row * 2] = g0;
            pair_expert[row * 2 + 1] = idx[1]; pair_gate[row * 2 + 1] = g1;
            atomicAdd(&blk_g[idx[0]], g0); atomicAdd(&blk_g[idx[1]], g1);
            atomicAdd(&blk_c[idx[0]], 1); atomicAdd(&blk_c[idx[1]], 1);
#pragma unroll
            for (int e = 0; e < 8; e++) {
                float thr = (nz[e] > thr_in) ? thr_in : thr_out;
                float z = (cl[e] - thr) / sd[e];
                float p = 0.5f * (1.f + erff(z * 0.70710678118654752f));
                atomicAdd(&blk_l[e], p);
            }
        }
    }
    __syncthreads();
    if (tid < NEXP) {
        atomicAdd(smf + SM_GSUM + tid, blk_g[tid]);
        atomicAdd(smf + SM_LSUM + tid, blk_l[tid]);
        atomicAdd(&small[SM_CNT + tid], blk_c[tid]);
    }
}

// ---------------- bucket prefix + scatter ----------------
__global__ void prefix_kernel(int* small) {
    if (threadIdx.x == 0 && blockIdx.x == 0) {
        int acc = 0;
        small[SM_AOFF] = 0;
        for (int e = 0; e < NEXP; e++) {
            acc += (small[SM_CNT + e] + 127) & ~127;
            small[SM_AOFF + e + 1] = acc;
        }
    }
}

// R1: block-aggregated scatter. R0 had 16384 device-scope atomicAdds on 8
// counters in ONE cacheline -> ~80us of serialized L2 atomics (top dispatch,
// VALUBusy 0.006). Now: LDS-atomic local ranks, then 8 global atomics per
// block (512 total, 32x fewer) to reserve ranges. Bucket-internal order is
// irrelevant (GEMM gathers rows; combine reads pair_pos).
__global__ __launch_bounds__(256) void scatter_kernel(const int* __restrict__ pair_expert, int* small,
                                                      int* __restrict__ bucket_rows, int* __restrict__ pair_pos) {
    __shared__ int blk_cnt[NEXP];
    __shared__ int blk_base[NEXP];
    int tid = threadIdx.x;
    if (tid < NEXP) blk_cnt[tid] = 0;
    __syncthreads();
    int p = blockIdx.x * 256 + tid;
    int e = pair_expert[p];
    int local = atomicAdd(&blk_cnt[e], 1);
    __syncthreads();
    if (tid < NEXP)
        blk_base[tid] = small[SM_AOFF + tid] + atomicAdd(&small[SM_CUR + tid], blk_cnt[tid]);
    __syncthreads();
    int pos = blk_base[e] + local;
    bucket_rows[pos] = p >> 1;
    pair_pos[p] = pos;
}

// ---------------- MFMA GEMM (A . B^T), 128x128 tile, BK=32 ----------------
// MODE 0: gathered x_norm @ W1[e]^T, +b1, SiLU, bf16 store to a_buf   (K=512,  N=1024)
// MODE 1: a_buf @ W2[e]^T, fp32 store to ypair                        (K=1024, N=512)
// MODE 2: x_bf @ owT^T, fp32 store to y                               (K=512,  N=512)
template <int MODE>
__global__ __launch_bounds__(256) void gemm_kernel(
    const u16* __restrict__ A, const u16* __restrict__ Bw,
    const int* __restrict__ bucket_rows, const int* __restrict__ small,
    const float* __restrict__ bias, const u16* __restrict__ zeropage,
    u16* __restrict__ out_bf, float* __restrict__ out_f)
{
    constexpr int KD = (MODE == 1) ? 1024 : 512;
    constexpr int ND = (MODE == 0) ? 1024 : 512;
    constexpr int SA = 40; // padded LDS row stride in shorts (80B: 16B-aligned, breaks pow2 banks)
    __shared__ __align__(16) u16 As[128 * SA];
    __shared__ __align__(16) u16 Bs[128 * SA];

    int tid = threadIdx.x;
    int e = 0;
    int base = blockIdx.x * 128;
    if constexpr (MODE == 0 || MODE == 1) {
        if (base >= small[SM_AOFF + 8]) return;
        while (e < 7 && base >= small[SM_AOFF + e + 1]) ++e;
    }

    const int srow = tid >> 2;       // 0..63
    const int scol = (tid & 3) * 8;  // 0,8,16,24 (x8 bf16 = 16B)
    const u16 *ap0, *ap1;
    if constexpr (MODE == 0) {
        int r0 = bucket_rows[base + srow];
        int r1 = bucket_rows[base + srow + 64];
        ap0 = (r0 < 0) ? zeropage : A + (size_t)r0 * KD;
        ap1 = (r1 < 0) ? zeropage : A + (size_t)r1 * KD;
    } else {
        ap0 = A + (size_t)(base + srow) * KD;
        ap1 = A + (size_t)(base + srow + 64) * KD;
    }
    const u16* Bsel = Bw + ((MODE == 2) ? 0 : (size_t)e * ND * KD);
    int bn = blockIdx.y * 128;
    const u16* bp0 = Bsel + (size_t)(bn + srow) * KD + scol;
    const u16* bp1 = Bsel + (size_t)(bn + srow + 64) * KD + scol;
    ap0 += scol; ap1 += scol;

    int wave = tid >> 6, lane = tid & 63;
    int wm = (wave & 1) * 64, wn = (wave >> 1) * 64;
    int fr = lane & 15, kg = (lane >> 4) * 8;

    float4v acc[4][4];
#pragma unroll
    for (int i = 0; i < 4; i++)
#pragma unroll
        for (int j = 0; j < 4; j++) acc[i][j] = (float4v){0.f, 0.f, 0.f, 0.f};

    for (int k0 = 0; k0 < KD; k0 += 32) {
        uint4 a0 = *(const uint4*)(ap0 + k0);
        uint4 a1 = *(const uint4*)(ap1 + k0);
        uint4 b0 = *(const uint4*)(bp0 + k0);
        uint4 b1 = *(const uint4*)(bp1 + k0);
        __syncthreads();
        *(uint4*)&As[srow * SA + scol] = a0;
        *(uint4*)&As[(srow + 64) * SA + scol] = a1;
        *(uint4*)&Bs[srow * SA + scol] = b0;
        *(uint4*)&Bs[(srow + 64) * SA + scol] = b1;
        __syncthreads();
        short8 af[4], bf[4];
#pragma unroll
        for (int mt = 0; mt < 4; mt++) af[mt] = *(const short8*)&As[(wm + mt * 16 + fr) * SA + kg];
#pragma unroll
        for (int nt = 0; nt < 4; nt++) bf[nt] = *(const short8*)&Bs[(wn + nt * 16 + fr) * SA + kg];
#pragma unroll
        for (int mt = 0; mt < 4; mt++)
#pragma unroll
            for (int nt = 0; nt < 4; nt++)
                acc[mt][nt] = __builtin_amdgcn_mfma_f32_16x16x32_bf16(af[mt], bf[nt], acc[mt][nt], 0, 0, 0);
    }

    // epilogue: C/D layout col=lane&15, row=(lane>>4)*4+reg (m89-verified)
    int rbase = (lane >> 4) * 4, c16 = lane & 15;
#pragma unroll
    for (int nt = 0; nt < 4; nt++) {
        int gn = bn + wn + nt * 16 + c16;
        float bv = 0.f;
        if constexpr (MODE == 0) bv = bias[e * ND + gn];
#pragma unroll
        for (int mt = 0; mt < 4; mt++) {
            int gm = base + wm + mt * 16 + rbase;
#pragma unroll
            for (int r = 0; r < 4; r++) {
                float v = acc[mt][nt][r];
                if constexpr (MODE == 0) {
                    float h = v + bv;
                    float a = h / (1.f + expf(-h)); // SiLU
                    out_bf[(size_t)(gm + r) * ND + gn] = f2bf(a);
                } else {
                    out_f[(size_t)(gm + r) * ND + gn] = v;
                }
            }
        }
    }
}

// ---------------- combine: y += sum_k gate_k * (ypair_k + b2[e_k]) ----------------
__global__ __launch_bounds__(128) void combine_kernel(
    float* __restrict__ y, const float* __restrict__ ypair,
    const int* __restrict__ pair_expert, const float* __restrict__ pair_gate,
    const int* __restrict__ pair_pos, const float* __restrict__ b2)
{
    int row = blockIdx.x;
    int e0 = pair_expert[row * 2], e1 = pair_expert[row * 2 + 1];
    float g0 = pair_gate[row * 2], g1 = pair_gate[row * 2 + 1];
    int p0 = pair_pos[row * 2], p1 = pair_pos[row * 2 + 1];
    int i = threadIdx.x; // 128 threads x float4 = 512 cols
    const float4* a0 = (const float4*)(ypair + (size_t)p0 * ODIM);
    const float4* a1 = (const float4*)(ypair + (size_t)p1 * ODIM);
    const float4* c0 = (const float4*)(b2 + (size_t)e0 * ODIM);
    const float4* c1 = (const float4*)(b2 + (size_t)e1 * ODIM);
    float4* yr = (float4*)(y + (size_t)row * ODIM);
    float4 v = yr[i], u0 = a0[i], u1 = a1[i], w0 = c0[i], w1 = c1[i];
    v.x += g0 * (u0.x + w0.x) + g1 * (u1.x + w1.x);
    v.y += g0 * (u0.y + w0.y) + g1 * (u1.y + w1.y);
    v.z += g0 * (u0.z + w0.z) + g1 * (u1.z + w1.z);
    v.w += g0 * (u0.w + w0.w) + g1 * (u1.w + w1.w);
    yr[i] = v;
}

// ---------------- loss + load ----------------
__global__ void loss_kernel(const int* __restrict__ small, float* __restrict__ out_loss, float* __restrict__ out_load) {
    if (threadIdx.x == 0 && blockIdx.x == 0) {
        const float* gs = (const float*)small + SM_GSUM;
        const float* ls = (const float*)small + SM_LSUM;
        float cv[2];
        for (int t = 0; t < 2; t++) {
            const float* v = t ? ls : gs;
            float m = 0.f;
            for (int e = 0; e < NEXP; e++) m += v[e];
            m *= (1.f / NEXP);
            float var = 0.f;
            for (int e = 0; e < NEXP; e++) { float d = v[e] - m; var += d * d; }
            var *= (1.f / NEXP);
            cv[t] = var / (m * m + 1e-10f);
        }
        out_loss[0] = 0.01f * (cv[0] + cv[1]);
        int tot = 0;
        for (int e = 0; e < NEXP; e++) tot += small[SM_CNT + e];
        float inv = 1.f / (float)tot;
        for (int e = 0; e < NEXP; e++) out_load[e] = (float)small[SM_CNT + e] * inv;
    }
}

extern "C" void kernel_launch(void* const* d_in, const int* in_sizes, int n_in,
                              void* d_out, int out_size, void* d_ws, size_t ws_size,
                              hipStream_t stream)
{
    (void)in_sizes; (void)n_in; (void)out_size; (void)ws_size;
    const float* x = (const float*)d_in[0];
    // d_in[1] x_offsets, d_in[2] max_seq_len: unused by the reference math
    const float* noise = (const float*)d_in[3];
    const float* norm_w = (const float*)d_in[4];
    const float* norm_b = (const float*)d_in[5];
    const float* w_gate = (const float*)d_in[6];
    const float* w_noise = (const float*)d_in[7];
    const float* W1 = (const float*)d_in[8];
    const float* b1 = (const float*)d_in[9];
    const float* W2 = (const float*)d_in[10];
    const float* b2 = (const float*)d_in[11];
    const float* ow = (const float*)d_in[12];

    float* y = (float*)d_out;
    float* out_loss = y + (size_t)N_ROWS * ODIM;
    float* out_load = out_loss + 1;

    char* ws = (char*)d_ws;
    size_t off = 0;
    auto alloc = [&](size_t b) { size_t p = off; off = (off + b + 255) & ~(size_t)255; return p; };
    u16* xnorm_bf = (u16*)(ws + alloc((size_t)N_ROWS * DDIM * 2));
    u16* x_bf     = (u16*)(ws + alloc((size_t)N_ROWS * DDIM * 2));
    u16* W1b      = (u16*)(ws + alloc((size_t)NEXP * HDIM * DDIM * 2));
    u16* W2b      = (u16*)(ws + alloc((size_t)NEXP * ODIM * HDIM * 2));
    u16* owT      = (u16*)(ws + alloc((size_t)DDIM * ODIM * 2));
    u16* a_buf    = (u16*)(ws + alloc((size_t)MAXPOS * HDIM * 2));
    float* ypair  = (float*)(ws + alloc((size_t)MAXPOS * ODIM * 4));
    int* pair_expert = (int*)(ws + alloc((size_t)MAXPAIRS * 4));
    float* pair_gate = (float*)(ws + alloc((size_t)MAXPAIRS * 4));
    int* pair_pos    = (int*)(ws + alloc((size_t)MAXPAIRS * 4));
    int* bucket_rows = (int*)(ws + alloc((size_t)MAXPOS * 4));
    int* small       = (int*)(ws + alloc(SM_WORDS * 4));
    float* zeropage  = (float*)(ws + alloc(2048));

    init_kernel<<<MAXPOS / 256, 256, 0, stream>>>(small, bucket_rows, zeropage);
    convert_w_kernel<<<8192, 256, 0, stream>>>(W1, W2, W1b, W2b);
    transpose_ow_kernel<<<dim3(16, 16), 256, 0, stream>>>(ow, owT);
    gating_kernel<<<N_ROWS / 16, 256, 0, stream>>>(x, noise, norm_w, norm_b, w_gate, w_noise,
                                                   xnorm_bf, x_bf, pair_expert, pair_gate, small);
    prefix_kernel<<<1, 1, 0, stream>>>(small);
    scatter_kernel<<<MAXPAIRS / 256, 256, 0, stream>>>(pair_expert, small, bucket_rows, pair_pos);
    gemm_kernel<0><<<dim3(MAXTILES, HDIM / 128), 256, 0, stream>>>(xnorm_bf, W1b, bucket_rows, small,
                                                                   b1, (const u16*)zeropage, a_buf, nullptr);
    gemm_kernel<1><<<dim3(MAXTILES, ODIM / 128), 256, 0, stream>>>(a_buf, W2b, bucket_rows, small,
                                                                   nullptr, (const u16*)zeropage, nullptr, ypair);
    gemm_kernel<2><<<dim3(N_ROWS / 128, ODIM / 128), 256, 0, stream>>>(x_bf, owT, bucket_rows, small,
                                                                       nullptr, (const u16*)zeropage, nullptr, y);
    combine_kernel<<<N_ROWS, 128, 0, stream>>>(y, ypair, pair_expert, pair_gate, pair_pos, b2);
    loss_kernel<<<1, 64, 0, stream>>>(small, out_loss, out_load);
}

// Round 3
// 275.586 us; speedup vs baseline: 1.2782x; 1.0152x over previous
//
#include <hip/hip_runtime.h>
#include <math.h>

typedef unsigned short u16;
typedef unsigned int u32;

#define N_ROWS 8192
#define DDIM 512
#define HDIM 1024
#define ODIM 512
#define NEXP 8
#define MAXPAIRS (N_ROWS * 2)          // 16384
#define MAXPOS (MAXPAIRS + NEXP * 128) // 17408 (per-expert segments 128-aligned)
#define MAXTILES (MAXPOS / 128)        // 136

// small-region word indices (in d_ws)
#define SM_CNT 0   // 8 ints: expert lengths
#define SM_CUR 8   // 8 ints: scatter cursors
#define SM_AOFF 16 // 9 ints: aligned bucket offsets
#define SM_GSUM 32 // 8 floats: sum of gates per expert
#define SM_LSUM 40 // 8 floats: sum of load_probs per expert
#define SM_WORDS 64

using short8 = __attribute__((ext_vector_type(8))) short;
using float4v = __attribute__((ext_vector_type(4))) float;

__device__ __forceinline__ u16 f2bf(float f) {
    union { float f; u32 u; } v; v.f = f;
    u32 u = v.u;
    return (u16)((u + 0x7fffu + ((u >> 16) & 1u)) >> 16);
}

// async global->LDS, 16B per lane; LDS dst = wave-uniform base + lane*16
__device__ __forceinline__ void async_copy16(u16* lds, const u16* g) {
    __builtin_amdgcn_global_load_lds(
        (const __attribute__((address_space(1))) void*)g,
        (__attribute__((address_space(3))) void*)lds, 16, 0, 0);
}

// ---------------- init ----------------
__global__ __launch_bounds__(256) void init_kernel(int* small, int* bucket_rows, float* zeropage) {
    int i = blockIdx.x * 256 + threadIdx.x;
    if (i < SM_WORDS) small[i] = 0;
    if (i < 512) zeropage[i] = 0.f; // 2 KB of zeros (gather target for padded rows)
    if (i < MAXPOS) bucket_rows[i] = -1;
}

// ---------------- weight conversion ----------------
__global__ __launch_bounds__(256) void convert_w_kernel(const float* __restrict__ W1, const float* __restrict__ W2,
                                                        u16* __restrict__ W1b, u16* __restrict__ W2b) {
    const size_t n4 = (size_t)NEXP * HDIM * DDIM / 4; // 1048576 float4s per matrix
    size_t i = (size_t)blockIdx.x * 256 + threadIdx.x;
    const float* src; u16* dst;
    if (i < n4) { src = W1; dst = W1b; } else { src = W2; dst = W2b; i -= n4; }
    float4 v = ((const float4*)src)[i];
    ushort4 o;
    o.x = f2bf(v.x); o.y = f2bf(v.y); o.z = f2bf(v.z); o.w = f2bf(v.w);
    ((ushort4*)dst)[i] = o;
}

__global__ __launch_bounds__(256) void transpose_ow_kernel(const float* __restrict__ ow, u16* __restrict__ owT) {
    // ow[d][o] (512x512) -> owT[o][d] bf16
    __shared__ float tile[32][33];
    int bx = blockIdx.x * 32, by = blockIdx.y * 32;
    int tx = threadIdx.x & 31, ty = threadIdx.x >> 5; // 32 x 8
    for (int r = ty; r < 32; r += 8) tile[r][tx] = ow[(size_t)(by + r) * ODIM + bx + tx];
    __syncthreads();
    for (int r = ty; r < 32; r += 8) owT[(size_t)(bx + r) * DDIM + by + tx] = f2bf(tile[tx][r]);
}

// ---------------- layernorm + gating ----------------
__global__ __launch_bounds__(256) void gating_kernel(
    const float* __restrict__ x, const float* __restrict__ noise,
    const float* __restrict__ norm_w, const float* __restrict__ norm_b,
    const float* __restrict__ w_gate, const float* __restrict__ w_noise,
    u16* __restrict__ xnorm_bf, u16* __restrict__ x_bf,
    int* __restrict__ pair_expert, float* __restrict__ pair_gate,
    int* __restrict__ small)
{
    __shared__ float wgT[NEXP * DDIM]; // [e][d] transposed -> conflict-free lane-stride-1 reads
    __shared__ float wnT[NEXP * DDIM];
    __shared__ float blk_g[NEXP];
    __shared__ float blk_l[NEXP];
    __shared__ int blk_c[NEXP];
    float* smf = (float*)small;

    int tid = threadIdx.x;
    for (int i = tid; i < NEXP * DDIM; i += 256) {
        int d = i >> 3, e = i & 7;
        wgT[e * DDIM + d] = w_gate[i];
        wnT[e * DDIM + d] = w_noise[i];
    }
    if (tid < NEXP) { blk_g[tid] = 0.f; blk_l[tid] = 0.f; blk_c[tid] = 0; }
    __syncthreads();

    int wave = tid >> 6, lane = tid & 63;
    float nw[8], nb[8];
#pragma unroll
    for (int j = 0; j < 8; j++) { nw[j] = norm_w[j * 64 + lane]; nb[j] = norm_b[j * 64 + lane]; }

    for (int r = 0; r < 4; ++r) {
        int row = blockIdx.x * 16 + wave * 4 + r;
        const float* xr = x + (size_t)row * DDIM;
        float xv[8], s = 0.f, s2 = 0.f;
#pragma unroll
        for (int j = 0; j < 8; j++) { float v = xr[j * 64 + lane]; xv[j] = v; s += v; s2 += v * v; }
#pragma unroll
        for (int o = 32; o; o >>= 1) { s += __shfl_xor(s, o, 64); s2 += __shfl_xor(s2, o, 64); }
        float mu = s * (1.f / DDIM);
        float var = s2 * (1.f / DDIM) - mu * mu;
        float rstd = rsqrtf(var + 1e-6f);

        float acc[16];
#pragma unroll
        for (int e = 0; e < 16; e++) acc[e] = 0.f;
#pragma unroll
        for (int j = 0; j < 8; j++) {
            float v = (xv[j] - mu) * rstd * nw[j] + nb[j];
            int d = j * 64 + lane;
            xnorm_bf[(size_t)row * DDIM + d] = f2bf(v);
            x_bf[(size_t)row * DDIM + d] = f2bf(xv[j]);
#pragma unroll
            for (int e = 0; e < 8; e++) {
                acc[e] += v * wgT[e * DDIM + d];
                acc[8 + e] += v * wnT[e * DDIM + d];
            }
        }
#pragma unroll
        for (int e = 0; e < 16; e++)
#pragma unroll
            for (int o = 32; o; o >>= 1) acc[e] += __shfl_xor(acc[e], o, 64);

        // all lanes now hold the full 16 logits; finish scalar gating math
        float cl[8], sd[8], nz[8];
#pragma unroll
        for (int e = 0; e < 8; e++) {
            cl[e] = acc[e];
            float t = acc[8 + e];
            float sp = fmaxf(t, 0.f) + log1pf(expf(-fabsf(t))); // stable softplus
            sd[e] = sp + 0.01f;
            nz[e] = cl[e] + noise[(size_t)row * NEXP + e] * sd[e];
        }
        // top-3 (strict > gives lowest-index tie-break, matching lax.top_k)
        int idx[3]; float val[3]; u32 msk = 0;
#pragma unroll
        for (int t = 0; t < 3; t++) {
            float best = -INFINITY; int bi = 0;
#pragma unroll
            for (int e = 0; e < 8; e++)
                if (!((msk >> e) & 1) && nz[e] > best) { best = nz[e]; bi = e; }
            idx[t] = bi; val[t] = best; msk |= 1u << bi;
        }
        float e1 = expf(val[1] - val[0]);
        float g0 = 1.f / (1.f + e1), g1 = e1 / (1.f + e1);
        float thr_in = val[2], thr_out = val[1];

        if (lane == 0) {
            pair_expert[row * 2] = idx[0]; pair_gate[row * 2] = g0;
            pair_expert[row * 2 + 1] = idx[1]; pair_gate[row * 2 + 1] = g1;
            atomicAdd(&blk_g[idx[0]], g0); atomicAdd(&blk_g[idx[1]], g1);
            atomicAdd(&blk_c[idx[0]], 1); atomicAdd(&blk_c[idx[1]], 1);
#pragma unroll
            for (int e = 0; e < 8; e++) {
                float thr = (nz[e] > thr_in) ? thr_in : thr_out;
                float z = (cl[e] - thr) / sd[e];
                float p = 0.5f * (1.f + erff(z * 0.70710678118654752f));
                atomicAdd(&blk_l[e], p);
            }
        }
    }
    __syncthreads();
    if (tid < NEXP) {
        atomicAdd(smf + SM_GSUM + tid, blk_g[tid]);
        atomicAdd(smf + SM_LSUM + tid, blk_l[tid]);
        atomicAdd(&small[SM_CNT + tid], blk_c[tid]);
    }
}

// ---------------- bucket prefix + scatter ----------------
__global__ void prefix_kernel(int* small) {
    if (threadIdx.x == 0 && blockIdx.x == 0) {
        int acc = 0;
        small[SM_AOFF] = 0;
        for (int e = 0; e < NEXP; e++) {
            acc += (small[SM_CNT + e] + 127) & ~127;
            small[SM_AOFF + e + 1] = acc;
        }
    }
}

// R1: block-aggregated scatter (512 global atomics instead of 16384 on one line)
__global__ __launch_bounds__(256) void scatter_kernel(const int* __restrict__ pair_expert, int* small,
                                                      int* __restrict__ bucket_rows, int* __restrict__ pair_pos) {
    __shared__ int blk_cnt[NEXP];
    __shared__ int blk_base[NEXP];
    int tid = threadIdx.x;
    if (tid < NEXP) blk_cnt[tid] = 0;
    __syncthreads();
    int p = blockIdx.x * 256 + tid;
    int e = pair_expert[p];
    int local = atomicAdd(&blk_cnt[e], 1);
    __syncthreads();
    if (tid < NEXP)
        blk_base[tid] = small[SM_AOFF + tid] + atomicAdd(&small[SM_CUR + tid], blk_cnt[tid]);
    __syncthreads();
    int pos = blk_base[e] + local;
    bucket_rows[pos] = p >> 1;
    pair_pos[p] = pos;
}

// ---------------- MFMA GEMM (A . B^T), 128x128 tile, BK=32, m97-style ----------------
// R2: global_load_lds width=16 staging (no VGPR round-trip, no staging VALU),
// unpadded [128][32] LDS layout (required: LDS dst is wave-uniform base + lane*16).
// Per-lane global addresses allow the MODE-0 row gather to stay.
// MODE 0: gathered x_norm @ W1[e]^T, +b1, SiLU, bf16 store to a_buf   (K=512,  N=1024)
// MODE 1: a_buf @ W2[e]^T, fp32 store to ypair                        (K=1024, N=512)
// MODE 2: x_bf @ owT^T, fp32 store to y                               (K=512,  N=512)
template <int MODE>
__global__ __launch_bounds__(256) void gemm_kernel(
    const u16* __restrict__ A, const u16* __restrict__ Bw,
    const int* __restrict__ bucket_rows, const int* __restrict__ small,
    const float* __restrict__ bias, const u16* __restrict__ zeropage,
    u16* __restrict__ out_bf, float* __restrict__ out_f)
{
    constexpr int KD = (MODE == 1) ? 1024 : 512;
    constexpr int ND = (MODE == 0) ? 1024 : 512;
    __shared__ __align__(16) u16 As[128 * 32]; // [row][k], 64B rows, lane-contiguous
    __shared__ __align__(16) u16 Bs[128 * 32];

    int tid = threadIdx.x;
    int e = 0;
    int base = blockIdx.x * 128;
    if constexpr (MODE == 0 || MODE == 1) {
        if (base >= small[SM_AOFF + 8]) return;
        while (e < 7 && base >= small[SM_AOFF + e + 1]) ++e;
    }

    int wave = tid >> 6, lane = tid & 63;
    // staging assignment: wave w covers tile rows [w*32, w*32+32); two insts of
    // 16 rows each; lane -> row w*32 + j*16 + (lane>>2), k-col (lane&3)*8
    const int trow = wave * 32 + (lane >> 2);
    const int kcol = (lane & 3) * 8;
    const u16 *ga0, *ga1;
    if constexpr (MODE == 0) {
        int r0 = bucket_rows[base + trow];
        int r1 = bucket_rows[base + trow + 16];
        ga0 = ((r0 < 0) ? zeropage : A + (size_t)r0 * KD) + kcol;
        ga1 = ((r1 < 0) ? zeropage : A + (size_t)r1 * KD) + kcol;
    } else {
        ga0 = A + (size_t)(base + trow) * KD + kcol;
        ga1 = A + (size_t)(base + trow + 16) * KD + kcol;
    }
    const u16* Bsel = Bw + ((MODE == 2) ? 0 : (size_t)e * ND * KD);
    int bn = blockIdx.y * 128;
    const u16* gb0 = Bsel + (size_t)(bn + trow) * KD + kcol;
    const u16* gb1 = Bsel + (size_t)(bn + trow + 16) * KD + kcol;
    u16* lA0 = &As[(wave * 32) * 32];
    u16* lA1 = &As[(wave * 32 + 16) * 32];
    u16* lB0 = &Bs[(wave * 32) * 32];
    u16* lB1 = &Bs[(wave * 32 + 16) * 32];

    int wm = (wave & 1) * 64, wn = (wave >> 1) * 64;
    int fr = lane & 15, kg = (lane >> 4) * 8;

    float4v acc[4][4];
#pragma unroll
    for (int i = 0; i < 4; i++)
#pragma unroll
        for (int j = 0; j < 4; j++) acc[i][j] = (float4v){0.f, 0.f, 0.f, 0.f};

    for (int k0 = 0; k0 < KD; k0 += 32) {
        __syncthreads(); // previous iter's LDS reads done before overwrite
        async_copy16(lA0, ga0 + k0);
        async_copy16(lA1, ga1 + k0);
        async_copy16(lB0, gb0 + k0);
        async_copy16(lB1, gb1 + k0);
        __syncthreads(); // drains vmcnt(0): staged data visible
        short8 af[4], bf[4];
#pragma unroll
        for (int mt = 0; mt < 4; mt++) af[mt] = *(const short8*)&As[(wm + mt * 16 + fr) * 32 + kg];
#pragma unroll
        for (int nt = 0; nt < 4; nt++) bf[nt] = *(const short8*)&Bs[(wn + nt * 16 + fr) * 32 + kg];
#pragma unroll
        for (int mt = 0; mt < 4; mt++)
#pragma unroll
            for (int nt = 0; nt < 4; nt++)
                acc[mt][nt] = __builtin_amdgcn_mfma_f32_16x16x32_bf16(af[mt], bf[nt], acc[mt][nt], 0, 0, 0);
    }

    // epilogue: C/D layout col=lane&15, row=(lane>>4)*4+reg (m89-verified)
    int rbase = (lane >> 4) * 4, c16 = lane & 15;
#pragma unroll
    for (int nt = 0; nt < 4; nt++) {
        int gn = bn + wn + nt * 16 + c16;
        float bv = 0.f;
        if constexpr (MODE == 0) bv = bias[e * ND + gn];
#pragma unroll
        for (int mt = 0; mt < 4; mt++) {
            int gm = base + wm + mt * 16 + rbase;
#pragma unroll
            for (int r = 0; r < 4; r++) {
                float v = acc[mt][nt][r];
                if constexpr (MODE == 0) {
                    float h = v + bv;
                    // fast SiLU: v_exp + v_rcp (abs err ~1e-6, threshold 4.8e-2)
                    float a = h * __builtin_amdgcn_rcpf(1.f + __expf(-h));
                    out_bf[(size_t)(gm + r) * ND + gn] = f2bf(a);
                } else {
                    out_f[(size_t)(gm + r) * ND + gn] = v;
                }
            }
        }
    }
}

// ---------------- combine: y += sum_k gate_k * (ypair_k + b2[e_k]) ----------------
__global__ __launch_bounds__(128) void combine_kernel(
    float* __restrict__ y, const float* __restrict__ ypair,
    const int* __restrict__ pair_expert, const float* __restrict__ pair_gate,
    const int* __restrict__ pair_pos, const float* __restrict__ b2)
{
    int row = blockIdx.x;
    int e0 = pair_expert[row * 2], e1 = pair_expert[row * 2 + 1];
    float g0 = pair_gate[row * 2], g1 = pair_gate[row * 2 + 1];
    int p0 = pair_pos[row * 2], p1 = pair_pos[row * 2 + 1];
    int i = threadIdx.x; // 128 threads x float4 = 512 cols
    const float4* a0 = (const float4*)(ypair + (size_t)p0 * ODIM);
    const float4* a1 = (const float4*)(ypair + (size_t)p1 * ODIM);
    const float4* c0 = (const float4*)(b2 + (size_t)e0 * ODIM);
    const float4* c1 = (const float4*)(b2 + (size_t)e1 * ODIM);
    float4* yr = (float4*)(y + (size_t)row * ODIM);
    float4 v = yr[i], u0 = a0[i], u1 = a1[i], w0 = c0[i], w1 = c1[i];
    v.x += g0 * (u0.x + w0.x) + g1 * (u1.x + w1.x);
    v.y += g0 * (u0.y + w0.y) + g1 * (u1.y + w1.y);
    v.z += g0 * (u0.z + w0.z) + g1 * (u1.z + w1.z);
    v.w += g0 * (u0.w + w0.w) + g1 * (u1.w + w1.w);
    yr[i] = v;
}

// ---------------- loss + load ----------------
__global__ void loss_kernel(const int* __restrict__ small, float* __restrict__ out_loss, float* __restrict__ out_load) {
    if (threadIdx.x == 0 && blockIdx.x == 0) {
        const float* gs = (const float*)small + SM_GSUM;
        const float* ls = (const float*)small + SM_LSUM;
        float cv[2];
        for (int t = 0; t < 2; t++) {
            const float* v = t ? ls : gs;
            float m = 0.f;
            for (int e = 0; e < NEXP; e++) m += v[e];
            m *= (1.f / NEXP);
            float var = 0.f;
            for (int e = 0; e < NEXP; e++) { float d = v[e] - m; var += d * d; }
            var *= (1.f / NEXP);
            cv[t] = var / (m * m + 1e-10f);
        }
        out_loss[0] = 0.01f * (cv[0] + cv[1]);
        int tot = 0;
        for (int e = 0; e < NEXP; e++) tot += small[SM_CNT + e];
        float inv = 1.f / (float)tot;
        for (int e = 0; e < NEXP; e++) out_load[e] = (float)small[SM_CNT + e] * inv;
    }
}

extern "C" void kernel_launch(void* const* d_in, const int* in_sizes, int n_in,
                              void* d_out, int out_size, void* d_ws, size_t ws_size,
                              hipStream_t stream)
{
    (void)in_sizes; (void)n_in; (void)out_size; (void)ws_size;
    const float* x = (const float*)d_in[0];
    // d_in[1] x_offsets, d_in[2] max_seq_len: unused by the reference math
    const float* noise = (const float*)d_in[3];
    const float* norm_w = (const float*)d_in[4];
    const float* norm_b = (const float*)d_in[5];
    const float* w_gate = (const float*)d_in[6];
    const float* w_noise = (const float*)d_in[7];
    const float* W1 = (const float*)d_in[8];
    const float* b1 = (const float*)d_in[9];
    const float* W2 = (const float*)d_in[10];
    const float* b2 = (const float*)d_in[11];
    const float* ow = (const float*)d_in[12];

    float* y = (float*)d_out;
    float* out_loss = y + (size_t)N_ROWS * ODIM;
    float* out_load = out_loss + 1;

    char* ws = (char*)d_ws;
    size_t off = 0;
    auto alloc = [&](size_t b) { size_t p = off; off = (off + b + 255) & ~(size_t)255; return p; };
    u16* xnorm_bf = (u16*)(ws + alloc((size_t)N_ROWS * DDIM * 2));
    u16* x_bf     = (u16*)(ws + alloc((size_t)N_ROWS * DDIM * 2));
    u16* W1b      = (u16*)(ws + alloc((size_t)NEXP * HDIM * DDIM * 2));
    u16* W2b      = (u16*)(ws + alloc((size_t)NEXP * ODIM * HDIM * 2));
    u16* owT      = (u16*)(ws + alloc((size_t)DDIM * ODIM * 2));
    u16* a_buf    = (u16*)(ws + alloc((size_t)MAXPOS * HDIM * 2));
    float* ypair  = (float*)(ws + alloc((size_t)MAXPOS * ODIM * 4));
    int* pair_expert = (int*)(ws + alloc((size_t)MAXPAIRS * 4));
    float* pair_gate = (float*)(ws + alloc((size_t)MAXPAIRS * 4));
    int* pair_pos    = (int*)(ws + alloc((size_t)MAXPAIRS * 4));
    int* bucket_rows = (int*)(ws + alloc((size_t)MAXPOS * 4));
    int* small       = (int*)(ws + alloc(SM_WORDS * 4));
    float* zeropage  = (float*)(ws + alloc(2048));

    init_kernel<<<MAXPOS / 256, 256, 0, stream>>>(small, bucket_rows, zeropage);
    convert_w_kernel<<<8192, 256, 0, stream>>>(W1, W2, W1b, W2b);
    transpose_ow_kernel<<<dim3(16, 16), 256, 0, stream>>>(ow, owT);
    gating_kernel<<<N_ROWS / 16, 256, 0, stream>>>(x, noise, norm_w, norm_b, w_gate, w_noise,
                                                   xnorm_bf, x_bf, pair_expert, pair_gate, small);
    prefix_kernel<<<1, 1, 0, stream>>>(small);
    scatter_kernel<<<MAXPAIRS / 256, 256, 0, stream>>>(pair_expert, small, bucket_rows, pair_pos);
    gemm_kernel<0><<<dim3(MAXTILES, HDIM / 128), 256, 0, stream>>>(xnorm_bf, W1b, bucket_rows, small,
                                                                   b1, (const u16*)zeropage, a_buf, nullptr);
    gemm_kernel<1><<<dim3(MAXTILES, ODIM / 128), 256, 0, stream>>>(a_buf, W2b, bucket_rows, small,
                                                                   nullptr, (const u16*)zeropage, nullptr, ypair);
    gemm_kernel<2><<<dim3(N_ROWS / 128, ODIM / 128), 256, 0, stream>>>(x_bf, owT, bucket_rows, small,
                                                                       nullptr, (const u16*)zeropage, nullptr, y);
    combine_kernel<<<N_ROWS, 128, 0, stream>>>(y, ypair, pair_expert, pair_gate, pair_pos, b2);
    loss_kernel<<<1, 64, 0, stream>>>(small, out_loss, out_load);
}